// Round 10
// baseline (142.070 us; speedup 1.0000x reference)
//
#include <hip/hip_runtime.h>

// PointGatedBlock: SE3 point conv + gated nonlinearity. fp32 in/out.
// R19 = R18 (62us) + two VALU/schedule attacks:
// (1) sched_group_barrier emission pinning in the m-loop body. R18 proved
//     source-level interleave is a no-op (dur/counters identical to R15):
//     hipcc re-clusters the body into phases (all trans, then all ds, then
//     all MFMA), so barrier-locked waves contend for one pipe at a time
//     (pipes sum: 33% VALU + 28% LDS + 13% MFMA + gaps = wall). The SGB
//     pattern forces {ds_read 2, mfma 2, valu 8, ds_write 1} x7 interleave
//     after {feat ds_write, anchor VALU, early global prefetch}.
// (2) GEMM2 W pre-permuted in cvt to Wp[a=(s3*4+q)][o][8] so af/ag addresses
//     are LINEAR in s3 (one add/step) -- kills div-13 magic-mul + mad64
//     chains (~1k VALU inst/thread in the tail).
// All else identical to R18: grid 512, 8 n-rows, reg-staged feat, phi+feat
// double-buffered, 1 barrier/iter, 67KB LDS, 2 blk/CU, (512,4), split-chain
// phi recurrence with overflow clamp.

typedef __attribute__((ext_vector_type(4))) float f32x4;
typedef __attribute__((ext_vector_type(8))) short s16x8;

#define DI 104
#define DO 144
#define TTST 1688          // Tt row stride (elems)
#define YST 9

#define W_ELEMS 239616     // 16*144*104 (stored permuted: Wp[208][144][8])
#define F_ELEMS 425984     // 4*104*1024
#define WP_BLKS 29952      // 208*144 8-elem groups

// LDS byte offsets (phi/feat rows: 64 elems = 128 B, XOR-swizzled blocks)
#define OFF_PHI0 0
#define OFF_PHI1 16384                  // 128*64*2
#define OFF_FEAT0 32768
#define OFF_FEAT1 47104                 // + 112*64*2 = 14336
#define OFF_Y 61440
#define SMEM_TOTAL (61440 + 144*9*4)    // 66624 B -> 2 blocks/CU

#define SGB(m, n) __builtin_amdgcn_sched_group_barrier((m), (n), 0)

__device__ __forceinline__ float fexp2(float x) {
#if __has_builtin(__builtin_amdgcn_exp2f)
    return __builtin_amdgcn_exp2f(x);
#else
    return exp2f(x);
#endif
}
__device__ __forceinline__ float flog2(float x) {
#if __has_builtin(__builtin_amdgcn_logf)
    return __builtin_amdgcn_logf(x);
#else
    return log2f(x);
#endif
}
__device__ __forceinline__ float fsqrt_(float x) {
#if __has_builtin(__builtin_amdgcn_sqrtf)
    return __builtin_amdgcn_sqrtf(x);
#else
    return sqrtf(x);
#endif
}
__device__ __forceinline__ float frcp_(float x) {
#if __has_builtin(__builtin_amdgcn_rcpf)
    return __builtin_amdgcn_rcpf(x);
#else
    return 1.0f / x;
#endif
}
__device__ __forceinline__ unsigned int pkbf(float lo, float hi) {
    unsigned int a = __builtin_bit_cast(unsigned int, lo) + 0x8000u;
    unsigned int b = __builtin_bit_cast(unsigned int, hi) + 0x8000u;
    return __builtin_amdgcn_perm(b, a, 0x07060302u);
}
__device__ __forceinline__ unsigned short f2b(float f) {
    return (unsigned short)((__builtin_bit_cast(unsigned int, f) + 0x8000u) >> 16);
}

// ---- pre-kernel: fp32 -> bf16. W goes in PERMUTED: Wp[a][o][8] with
// a = k*13 + ib (the (k, i-block) walk order of GEMM2), so GEMM2 addresses
// are linear in its loop counter. feat unchanged at ws[W_ELEMS..).
__global__ __launch_bounds__(256, 8)
void cvt_kernel(const float* __restrict__ feat_g, const float* __restrict__ W_g,
                unsigned short* __restrict__ ws)
{
    int gid = blockIdx.x * 256 + threadIdx.x;           // 8 elems per thread
    const float* src;
    unsigned short* dst;
    if (gid < WP_BLKS) {
        int a = gid / 144;
        int o = gid - a * 144;
        int k = a / 13;
        int im = (a - k * 13) << 3;
        src = W_g + ((k * DO + o) * DI + im);
        dst = ws + gid * 8;
    } else {
        int g2 = gid - WP_BLKS;
        src = feat_g + g2 * 8;
        dst = ws + W_ELEMS + g2 * 8;
    }
    f32x4 a = *(const f32x4*)src;
    f32x4 b = *(const f32x4*)(src + 4);
    unsigned int o[4] = { pkbf(a[0],a[1]), pkbf(a[2],a[3]), pkbf(b[0],b[1]), pkbf(b[2],b[3]) };
    *(f32x4*)dst = *(f32x4*)o;
}

// load-tile macro: diff/mask regs for this thread's (n-row, 2 m cols) at m-base M0
#define LOAD_DM(M0)                                                    \
    do {                                                               \
        const float* dp_ = diff_g + (dmrow + (M0) + pml)*3;            \
        dx0 = dp_[0]; dy0 = dp_[1]; dz0 = dp_[2];                      \
        dx1 = dp_[3]; dy1 = dp_[4]; dz1 = dp_[5];                      \
        const float* mp_ = mask_g + dmrow + (M0) + pml;                \
        mk0 = mp_[0]; mk1 = mp_[1];                                    \
    } while (0)

#define LOAD_FEAT(M0)                                                          \
    do {                                                                       \
        fr0 = *(const s16x8*)(featbf + fbase + ((size_t)fi0 << 10) + (M0) + (fj << 3)); \
        if (t < 320)                                                           \
            fr1 = *(const s16x8*)(featbf + fbase + ((size_t)fi1 << 10) + (M0) + (fj << 3)); \
    } while (0)

// phi anchors: chain A (k 0-3) via 4 exp2; chain B (k 4-7) derived via muls
// with the 4th power CLAMPED (when clamp engages va is provably 0 -> vb = 0
// exactly; avoids 0*inf = NaN, R17 bug).
#define PHI_ANCHOR()                                                   \
    do {                                                               \
        float r0_ = fsqrt_(fmaf(dx0,dx0, fmaf(dy0,dy0, fmaf(dz0,dz0, 1e-12f)))); \
        float r1_ = fsqrt_(fmaf(dx1,dx1, fmaf(dy1,dy1, fmaf(dz1,dz1, 1e-12f)))); \
        float t0_ = r0_ - K0OFF, t1_ = r1_ - K0OFF;                    \
        va0 = fexp2(fmaf(CEXP*t0_, t0_, flog2(mk0)));                  \
        va1 = fexp2(fmaf(CEXP*t1_, t1_, flog2(mk1)));                  \
        wa0 = fexp2(fmaf(A1, r0_, S0B));                               \
        wa1 = fexp2(fmaf(A1, r1_, S0B));                               \
        float p0_ = wa0*wa0, p1_ = wa1*wa1;                            \
        float q0_ = fminf(p0_*p0_, 3.0e38f);                           \
        float q1_ = fminf(p1_*p1_, 3.0e38f);                           \
        vb0 = va0 * q0_ * U2_6;                                        \
        vb1 = va1 * q1_ * U2_6;                                        \
        wb0 = wa0 * U2_4;                                              \
        wb1 = wa1 * U2_4;                                              \
    } while (0)

// write one 4-k quad (rows J0..J0+3) from its chain; v,w advanced in place
#define PHI_WRITE_Q(BUF, V0, V1, W0, W1, J0)                           \
    do {                                                               \
        unsigned short* pw_ = (BUF) + phirow;                          \
        _Pragma("unroll")                                              \
        for (int j_ = 0; j_ < 4; ++j_) {                               \
            *(unsigned int*)(pw_ + ((J0) + j_)*64 + ((pblk ^ ((J0) + j_)) << 3)) = pkbf(V0, V1); \
            V0 *= W0; W0 *= U2;                                        \
            V1 *= W1; W1 *= U2;                                        \
        }                                                              \
    } while (0)

#define WRITE_FEAT(BUF)                                                \
    do {                                                               \
        *(s16x8*)((BUF) + fi0*64 + fjs) = fr0;                         \
        if (t < 320) *(s16x8*)((BUF) + fi1*64 + fjs) = fr1;            \
    } while (0)

// one kk-half of GEMM1 (2 A-reads, up to 4 B-reads, up to 8 MFMAs)
#define GEMM1_HALF(PBUF, FBUF, KK)                                     \
    do {                                                               \
        const int mo_ = (((KK)*4 + q) ^ sw) << 3;                      \
        s16x8 a0_ = *(const s16x8*)((PBUF) + ((2*wr    )*16 + l15)*64 + mo_); \
        s16x8 a1_ = *(const s16x8*)((PBUF) + ((2*wr + 1)*16 + l15)*64 + mo_); \
        _Pragma("unroll")                                              \
        for (int cc_ = 0; cc_ < 4; ++cc_) {                            \
            if (ct0 + cc_ < 7) {                                       \
                s16x8 bf_ = *(const s16x8*)((FBUF) + ((ct0+cc_)*16 + l15)*64 + mo_); \
                acc[0][cc_] = __builtin_amdgcn_mfma_f32_16x16x32_bf16(a0_, bf_, acc[0][cc_], 0, 0, 0); \
                acc[1][cc_] = __builtin_amdgcn_mfma_f32_16x16x32_bf16(a1_, bf_, acc[1][cc_], 0, 0, 0); \
            }                                                          \
        }                                                              \
    } while (0)

__global__ __launch_bounds__(512, 4)
void pgb_kernel(const unsigned short* __restrict__ ws,   // Wp | featbf
                const float* __restrict__ diff_g,
                const float* __restrict__ mask_g,
                float* __restrict__ out_g)
{
    const unsigned short* Wp     = ws;                   // [208][144][8] bf16
    const unsigned short* featbf = ws + W_ELEMS;

    __shared__ __align__(16) unsigned char smem[SMEM_TOTAL];
    unsigned short* Tt   = (unsigned short*)smem;        // aliases phi bufs (post-barrier)
    float*          ylds = (float*)(smem + OFF_Y);
    unsigned short* phi0b  = (unsigned short*)(smem + OFF_PHI0);
    unsigned short* phi1b  = (unsigned short*)(smem + OFF_PHI1);
    unsigned short* feat0b = (unsigned short*)(smem + OFF_FEAT0);
    unsigned short* feat1b = (unsigned short*)(smem + OFF_FEAT1);

    const int t    = threadIdx.x;
    const int b    = blockIdx.x >> 7;
    const int n0   = (blockIdx.x & 127) << 3;
    const int wave = t >> 6;
    const int lane = t & 63;
    const int l15  = lane & 15;
    const int q    = lane >> 4;
    const int wr   = wave >> 1;          // rowgroup: rowtiles 2wr, 2wr+1 (n_local)
    const int ct0  = (wave & 1) << 2;    // colgroup: coltiles ct0..ct0+3 (skip 7)
    const int sw   = l15 & 7;            // read-side swizzle key (row&7)

    // zero feat pad rows 104..111 in both buffers
    if (t < 256) {
        ((unsigned int*)(smem + OFF_FEAT0 + DI*128))[t] = 0u;
        ((unsigned int*)(smem + OFF_FEAT1 + DI*128))[t] = 0u;
    }

    f32x4 acc[2][4];
#pragma unroll
    for (int rr = 0; rr < 2; ++rr)
#pragma unroll
        for (int cc = 0; cc < 4; ++cc)
            acc[rr][cc] = (f32x4){0.f, 0.f, 0.f, 0.f};

    // phi thread mapping: 8 n x 2 k-halves x 32 m-pairs
    const int pn   = t >> 6;             // n-row 0..7 (== wave)
    const int kh   = (t >> 5) & 1;       // k-half: k0 = 8*kh
    const int pml  = (t & 31) << 1;      // m pair (even), 0..62
    const int pblk = (t & 31) >> 2;      // m block 0..7 (write-side swizzle base)
    const int phirow = (pn*16 + kh*8)*64 + (pml & 7);   // phi write base (elems)
    const float CEXP = -23.083120654223414f;   // -GAMMA * log2(e)
    const float A1   = 6.155498841126244f;     // -2*CEXP*DL
    const float V2   = -0.8207331788168325f;   // 2*CEXP*DL^2
    const float U2   = fexp2(V2);              // 2^V2 (uniform)
    const float U2_2 = U2*U2;
    const float U2_4 = U2_2*U2_2;              // 2^(4 V2)
    const float U2_6 = U2_4*U2_2;              // 2^(6 V2)
    const float K0OFF = kh ? 1.0666666666666667f : 0.f;
    const float S0B   = kh ? -6.976232019943076f : -0.41036658940841624f;
    const size_t dmrow = (size_t)((b << 10) + n0 + pn) << 10;

    // feat staging mapping
    const int fi0 = t >> 3, fj = t & 7;
    const int fi1 = 64 + (t >> 3);
    const int fjs = (fj ^ (fi0 & 7)) << 3;
    const size_t fbase = (size_t)b * DI << 10;

    float dx0, dy0, dz0, dx1, dy1, dz1, mk0, mk1;
    s16x8 fr0 = {}, fr1 = {};
    float va0, va1, wa0, wa1, vb0, vb1, wb0, wb1;

    // ---- prologue: tile 0 -> buf0; then preload tile 1 regs ----
    LOAD_DM(0);
    LOAD_FEAT(0);
    PHI_ANCHOR();
    PHI_WRITE_Q(phi0b, va0, va1, wa0, wa1, 0);
    PHI_WRITE_Q(phi0b, vb0, vb1, wb0, wb1, 4);
    WRITE_FEAT(feat0b);
    LOAD_DM(64);
    LOAD_FEAT(64);

    // ---- main loop: iter s reads buf(s&1), writes tile s+1 -> buf(~s&1).
    for (int s = 0; s < 15; ++s) {
        unsigned short* rp = (s & 1) ? phi1b  : phi0b;
        unsigned short* rf = (s & 1) ? feat1b : feat0b;
        unsigned short* wp = (s & 1) ? phi0b  : phi1b;
        unsigned short* wf = (s & 1) ? feat0b : feat1b;
        __syncthreads();
        WRITE_FEAT(wf);                 // tile s+1 from fr regs (before reload)
        PHI_ANCHOR();                   // tile s+1 from dm regs (before reload)
        GEMM1_HALF(rp, rf, 0);          // tile s, independent of phi
        PHI_WRITE_Q(wp, va0, va1, wa0, wa1, 0);
        GEMM1_HALF(rp, rf, 1);
        PHI_WRITE_Q(wp, vb0, vb1, wb0, wb1, 4);
        {
            const int mnext = (s < 14 ? (s + 2) : 15) * 64;
            LOAD_DM(mnext);             // consumed next iter -> full-iter cover
            LOAD_FEAT(mnext);
        }
        // ---- emission pinning: stop the scheduler from re-clustering the
        // body into phases. Desired order: feat writes + anchor launch +
        // early prefetch, then 7x {ds_read 2, mfma 2, valu 8, ds_write 1}.
        SGB(0x200, 2);                  // DS_WRITE: feat staging
        SGB(0x002, 10);                 // VALU: anchor chains launch
        SGB(0x020, 6);                  // VMEM_READ: prefetch loads issue early
#pragma unroll
        for (int g = 0; g < 7; ++g) {
            SGB(0x100, 2);              // DS_READ (phi/feat fragments)
            SGB(0x008, 2);              // MFMA
            SGB(0x002, 8);              // VALU (recurrence + pkbf)
            SGB(0x200, 1);              // DS_WRITE (phi quads)
        }
    }
    __syncthreads();
    GEMM1_HALF(phi1b, feat1b, 0);       // tail: tile 15 lives in buf1
    GEMM1_HALF(phi1b, feat1b, 1);

    __syncthreads();   // phi bufs free -> Tt may overwrite

    // ---- acc (C: col=l15=i_local, row=q*4+r=k; tiles (n_local, i-tile)) -> Tt[n][k*104+i]
#pragma unroll
    for (int rr = 0; rr < 2; ++rr) {
        int nloc = 2*wr + rr;
#pragma unroll
        for (int cc = 0; cc < 4; ++cc) {
            int i = (ct0+cc)*16 + l15;
            if (ct0 + cc < 7 && i < DI) {
#pragma unroll
                for (int r = 0; r < 4; ++r)
                    Tt[nloc*TTST + (q*4+r)*DI + i] = f2b(acc[rr][cc][r]);
            }
        }
    }
    __syncthreads();

    // ---- GEMM2: y[o,n] = sum_ki Wp[a][o]*Tt[n][a-block]; 52 K-steps of 32.
    // Wp pre-permuted: af/ag addresses LINEAR in s3 (no div/mod, no mad64).
    f32x4 y0 = (f32x4){0.f,0.f,0.f,0.f}, y1 = (f32x4){0.f,0.f,0.f,0.f};
    const unsigned short* wp0 = Wp + ((size_t)q*144 + (wave*16 + l15))*8;
    const unsigned short* wp1 = Wp + ((size_t)q*144 + (128 + l15))*8;
#pragma unroll 4
    for (int s3 = 0; s3 < 52; ++s3) {
        s16x8 bf = *(const s16x8*)(Tt + (l15 & 7)*TTST + s3*32 + q*8);
        s16x8 af = *(const s16x8*)(wp0 + (size_t)s3*4608);   // 4*144*8 elems/step
        y0 = __builtin_amdgcn_mfma_f32_16x16x32_bf16(af, bf, y0, 0, 0, 0);
        if (wave == 0) {
            s16x8 ag = *(const s16x8*)(wp1 + (size_t)s3*4608);
            y1 = __builtin_amdgcn_mfma_f32_16x16x32_bf16(ag, bf, y1, 0, 0, 0);
        }
    }
    if (l15 < 8) {
#pragma unroll
        for (int r = 0; r < 4; ++r)
            ylds[(wave*16 + q*4 + r)*YST + l15] = y0[r];
        if (wave == 0) {
#pragma unroll
            for (int r = 0; r < 4; ++r)
                ylds[(128 + q*4 + r)*YST + l15] = y1[r];
        }
    }
    __syncthreads();

    // ---- gating epilogue: out[b, o(<120), n0+nn] fp32 ----
    const float L2E = 1.4426950408889634f;
    for (int idx = t; idx < 120*8; idx += 512) {
        int o = idx >> 3, nn = idx & 7;
        float y = ylds[o*YST + nn];
        float v;
        if (o < 32) {
            v = fmaxf(y, 0.f);
        } else if (o < 80) {
            float g = ylds[(120 + (o-32)/3)*YST + nn];
            v = y * frcp_(1.f + fexp2(-g*L2E));
        } else {
            float g = ylds[(136 + (o-80)/5)*YST + nn];
            v = y * frcp_(1.f + fexp2(-g*L2E));
        }
        out_g[((size_t)(b*120 + o) << 10) + n0 + nn] = v;
    }
}

extern "C" void kernel_launch(void* const* d_in, const int* in_sizes, int n_in,
                              void* d_out, int out_size, void* d_ws, size_t ws_size,
                              hipStream_t stream) {
    const float* feat = (const float*)d_in[0];  // [4,104,1024] fp32
    const float* diff = (const float*)d_in[1];  // [4,1024,1024,3] fp32
    const float* mask = (const float*)d_in[2];  // [4,1024,1024] fp32
    const float* W    = (const float*)d_in[3];  // [16,144,104] fp32
    float* out = (float*)d_out;                 // [4,120,1024] fp32
    unsigned short* ws = (unsigned short*)d_ws; // Wp (479 KB) + featbf (852 KB)
    (void)in_sizes; (void)n_in; (void)out_size; (void)ws_size;
    cvt_kernel<<<dim3((W_ELEMS + F_ELEMS)/8/256), dim3(256), 0, stream>>>(feat, W, ws);
    pgb_kernel<<<dim3(512), dim3(512), 0, stream>>>(ws, diff, mask, out);
}

// Round 11
// 141.615 us; speedup vs baseline: 1.0032x; 1.0032x over previous
//
#include <hip/hip_runtime.h>

// PointGatedBlock: SE3 point conv + gated nonlinearity. fp32 in/out.
// R20 = producer/consumer WAVE SPECIALIZATION (AITER pattern). R9-R19 proved:
// occupancy is not the lever (R14/R16), source interleave is a no-op (R18),
// SGB pinning is a no-op (R19), VALU cuts give ~1.5us each. All pipes <35%
// because every wave runs the same serial phase chain barrier-locked -> pipes
// take turns. Fix: waves 0-3 = PRODUCERS (diff/mask loads, phi trans+writes,
// feat staging: VALU/trans/DS-write/VMEM pipes); waves 4-7 = CONSUMERS
// (GEMM1 = DS-read+MFMA, acc[2][7]=56 VGPR per wave, one rowgroup x all 7
// coltiles). Disjoint per-role loops (16 barriers each side, count-matched;
// AMD s_barrier is arrival-count based) keep register liveness separate.
// Producer phi: 4 m-cols/thread, sequential per-col recurrence (2 exp2 +
// 7x2 muls per col; overflow-immune). diff loads = 3x f32x4 (aligned: m0%4=0).
// Same LDS layout/swizzles as R19; GEMM2 Wp-linear kept; grid 512, 67KB LDS,
// 2 blk/CU, (512,4).

typedef __attribute__((ext_vector_type(4))) float f32x4;
typedef __attribute__((ext_vector_type(8))) short s16x8;

#define DI 104
#define DO 144
#define TTST 1688          // Tt row stride (elems)
#define YST 9

#define W_ELEMS 239616     // 16*144*104 (stored permuted: Wp[208][144][8])
#define F_ELEMS 425984     // 4*104*1024
#define WP_BLKS 29952      // 208*144 8-elem groups

// LDS byte offsets (phi/feat rows: 64 elems = 128 B, XOR-swizzled blocks)
#define OFF_PHI0 0
#define OFF_PHI1 16384                  // 128*64*2
#define OFF_FEAT0 32768
#define OFF_FEAT1 47104                 // + 112*64*2 = 14336
#define OFF_Y 61440
#define SMEM_TOTAL (61440 + 144*9*4)    // 66624 B -> 2 blocks/CU

__device__ __forceinline__ float fexp2(float x) {
#if __has_builtin(__builtin_amdgcn_exp2f)
    return __builtin_amdgcn_exp2f(x);
#else
    return exp2f(x);
#endif
}
__device__ __forceinline__ float flog2(float x) {
#if __has_builtin(__builtin_amdgcn_logf)
    return __builtin_amdgcn_logf(x);
#else
    return log2f(x);
#endif
}
__device__ __forceinline__ float fsqrt_(float x) {
#if __has_builtin(__builtin_amdgcn_sqrtf)
    return __builtin_amdgcn_sqrtf(x);
#else
    return sqrtf(x);
#endif
}
__device__ __forceinline__ float frcp_(float x) {
#if __has_builtin(__builtin_amdgcn_rcpf)
    return __builtin_amdgcn_rcpf(x);
#else
    return 1.0f / x;
#endif
}
__device__ __forceinline__ unsigned int pkbf(float lo, float hi) {
    unsigned int a = __builtin_bit_cast(unsigned int, lo) + 0x8000u;
    unsigned int b = __builtin_bit_cast(unsigned int, hi) + 0x8000u;
    return __builtin_amdgcn_perm(b, a, 0x07060302u);
}
__device__ __forceinline__ unsigned short f2b(float f) {
    return (unsigned short)((__builtin_bit_cast(unsigned int, f) + 0x8000u) >> 16);
}

// ---- pre-kernel: fp32 -> bf16. W permuted: Wp[a][o][8], a = k*13 + ib ----
__global__ __launch_bounds__(256, 8)
void cvt_kernel(const float* __restrict__ feat_g, const float* __restrict__ W_g,
                unsigned short* __restrict__ ws)
{
    int gid = blockIdx.x * 256 + threadIdx.x;           // 8 elems per thread
    const float* src;
    unsigned short* dst;
    if (gid < WP_BLKS) {
        int a = gid / 144;
        int o = gid - a * 144;
        int k = a / 13;
        int im = (a - k * 13) << 3;
        src = W_g + ((k * DO + o) * DI + im);
        dst = ws + gid * 8;
    } else {
        int g2 = gid - WP_BLKS;
        src = feat_g + g2 * 8;
        dst = ws + W_ELEMS + g2 * 8;
    }
    f32x4 a = *(const f32x4*)src;
    f32x4 b = *(const f32x4*)(src + 4);
    unsigned int o[4] = { pkbf(a[0],a[1]), pkbf(a[2],a[3]), pkbf(b[0],b[1]), pkbf(b[2],b[3]) };
    *(f32x4*)dst = *(f32x4*)o;
}

// ---- producer: load diff/mask (4 m-cols) + feat (4 chunks) for tile M0 ----
#define PROD_LOAD(M0)                                                  \
    do {                                                               \
        const float* dp_ = diff_g + (dmrow + (M0) + m0)*3;             \
        dA = *(const f32x4*)dp_;                                       \
        dB = *(const f32x4*)(dp_ + 4);                                 \
        dC = *(const f32x4*)(dp_ + 8);                                 \
        mkv = *(const f32x4*)(mask_g + dmrow + (M0) + m0);             \
        if (t < 208) {                                                 \
            const unsigned short* fp_ = featbf + fbase + ((size_t)frow << 10) + (M0) + (fc0 << 3); \
            f0 = *(const s16x8*)(fp_);                                 \
            f1 = *(const s16x8*)(fp_ + 8);                             \
            f2 = *(const s16x8*)(fp_ + 16);                            \
            f3 = *(const s16x8*)(fp_ + 24);                            \
        }                                                              \
    } while (0)

// ---- producer: phi (8 k-rows x 4 m-cols, sequential recurrence per col)
// + feat staging writes, into the given buffers ----
#define PROD_WRITE(PBUF, FBUF)                                         \
    do {                                                               \
        float v0_, v1_, v2_, v3_, w0_, w1_, w2_, w3_;                  \
        { float r_ = fsqrt_(fmaf(dA[0],dA[0], fmaf(dA[1],dA[1], fmaf(dA[2],dA[2], 1e-12f)))); \
          float tt_ = r_ - K0OFF;                                      \
          v0_ = fexp2(fmaf(CEXP*tt_, tt_, flog2(mkv[0])));             \
          w0_ = fexp2(fmaf(A1, r_, S0B)); }                            \
        { float r_ = fsqrt_(fmaf(dA[3],dA[3], fmaf(dB[0],dB[0], fmaf(dB[1],dB[1], 1e-12f)))); \
          float tt_ = r_ - K0OFF;                                      \
          v1_ = fexp2(fmaf(CEXP*tt_, tt_, flog2(mkv[1])));             \
          w1_ = fexp2(fmaf(A1, r_, S0B)); }                            \
        { float r_ = fsqrt_(fmaf(dB[2],dB[2], fmaf(dB[3],dB[3], fmaf(dC[0],dC[0], 1e-12f)))); \
          float tt_ = r_ - K0OFF;                                      \
          v2_ = fexp2(fmaf(CEXP*tt_, tt_, flog2(mkv[2])));             \
          w2_ = fexp2(fmaf(A1, r_, S0B)); }                            \
        { float r_ = fsqrt_(fmaf(dC[1],dC[1], fmaf(dC[2],dC[2], fmaf(dC[3],dC[3], 1e-12f)))); \
          float tt_ = r_ - K0OFF;                                      \
          v3_ = fexp2(fmaf(CEXP*tt_, tt_, flog2(mkv[3])));             \
          w3_ = fexp2(fmaf(A1, r_, S0B)); }                            \
        unsigned short* pw_ = (PBUF) + pbase;                          \
        _Pragma("unroll")                                              \
        for (int j_ = 0; j_ < 8; ++j_) {                               \
            unsigned long long pk_ = (unsigned long long)pkbf(v0_, v1_) \
                                   | ((unsigned long long)pkbf(v2_, v3_) << 32); \
            *(unsigned long long*)(pw_ + j_*64 + ((pmblk ^ j_) << 3)) = pk_; \
            v0_ *= w0_; w0_ *= U2;                                     \
            v1_ *= w1_; w1_ *= U2;                                     \
            v2_ *= w2_; w2_ *= U2;                                     \
            v3_ *= w3_; w3_ *= U2;                                     \
        }                                                              \
        if (t < 208) {                                                 \
            unsigned short* fw_ = (FBUF) + frow*64;                    \
            *(s16x8*)(fw_ + (((fc0    ) ^ fsw) << 3)) = f0;            \
            *(s16x8*)(fw_ + (((fc0 + 1) ^ fsw) << 3)) = f1;            \
            *(s16x8*)(fw_ + (((fc0 + 2) ^ fsw) << 3)) = f2;            \
            *(s16x8*)(fw_ + (((fc0 + 3) ^ fsw) << 3)) = f3;            \
        }                                                              \
    } while (0)

// ---- consumer: one rowgroup (n = 2c, 2c+1) x all 7 coltiles ----
#define GEMM1_7(PBUF, FBUF)                                            \
    do {                                                               \
        _Pragma("unroll")                                              \
        for (int kk_ = 0; kk_ < 2; ++kk_) {                            \
            const int mo_ = ((kk_*4 + q) ^ sw) << 3;                   \
            s16x8 a0_ = *(const s16x8*)((PBUF) + (c*32      + l15)*64 + mo_); \
            s16x8 a1_ = *(const s16x8*)((PBUF) + (c*32 + 16 + l15)*64 + mo_); \
            _Pragma("unroll")                                          \
            for (int ct_ = 0; ct_ < 7; ++ct_) {                        \
                s16x8 bf_ = *(const s16x8*)((FBUF) + (ct_*16 + l15)*64 + mo_); \
                acc0[ct_] = __builtin_amdgcn_mfma_f32_16x16x32_bf16(a0_, bf_, acc0[ct_], 0, 0, 0); \
                acc1[ct_] = __builtin_amdgcn_mfma_f32_16x16x32_bf16(a1_, bf_, acc1[ct_], 0, 0, 0); \
            }                                                          \
        }                                                              \
    } while (0)

__global__ __launch_bounds__(512, 4)
void pgb_kernel(const unsigned short* __restrict__ ws,   // Wp | featbf
                const float* __restrict__ diff_g,
                const float* __restrict__ mask_g,
                float* __restrict__ out_g)
{
    const unsigned short* Wp     = ws;                   // [208][144][8] bf16
    const unsigned short* featbf = ws + W_ELEMS;

    __shared__ __align__(16) unsigned char smem[SMEM_TOTAL];
    unsigned short* Tt   = (unsigned short*)smem;        // aliases phi bufs (post-loop)
    float*          ylds = (float*)(smem + OFF_Y);
    unsigned short* phi0b  = (unsigned short*)(smem + OFF_PHI0);
    unsigned short* phi1b  = (unsigned short*)(smem + OFF_PHI1);
    unsigned short* feat0b = (unsigned short*)(smem + OFF_FEAT0);
    unsigned short* feat1b = (unsigned short*)(smem + OFF_FEAT1);

    const int t    = threadIdx.x;
    const int b    = blockIdx.x >> 7;
    const int n0   = (blockIdx.x & 127) << 3;
    const int wave = t >> 6;
    const int lane = t & 63;
    const int l15  = lane & 15;
    const int q    = lane >> 4;

    // zero feat pad rows 104..111 in both buffers (threads 0..255 = producers)
    if (t < 256) {
        ((unsigned int*)(smem + OFF_FEAT0 + DI*128))[t] = 0u;
        ((unsigned int*)(smem + OFF_FEAT1 + DI*128))[t] = 0u;
    }

    f32x4 acc0[7], acc1[7];              // consumer accumulators (live on
                                         // consumer path only -> no pressure
                                         // overlap with producer state)

    if (wave < 4) {
        // ================= PRODUCER waves 0-3 =================
        const int pn    = t >> 5;        // n-row 0..7
        const int kh    = (t >> 4) & 1;  // k-half: k0 = 8*kh
        const int mg    = t & 15;        // m-group: cols m0..m0+3
        const int m0    = mg << 2;
        const int pmblk = mg >> 1;       // 8-elem block index of m0
        const int pbase = (pn*16 + kh*8)*64 + (m0 & 7);
        const int frow  = t >> 1;        // feat row 0..103 (t<208)
        const int fc0   = (t & 1) << 2;  // first 16B chunk (of 8) in the row
        const int fsw   = frow & 7;
        const float CEXP = -23.083120654223414f;   // -GAMMA * log2(e)
        const float A1   = 6.155498841126244f;     // -2*CEXP*DL
        const float V2   = -0.8207331788168325f;   // 2*CEXP*DL^2
        const float U2   = fexp2(V2);
        const float K0OFF = kh ? 1.0666666666666667f : 0.f;
        const float S0B   = kh ? -6.976232019943076f : -0.41036658940841624f;
        const size_t dmrow = (size_t)((b << 10) + n0 + pn) << 10;
        const size_t fbase = (size_t)b * DI << 10;

        f32x4 dA, dB, dC, mkv;
        s16x8 f0 = {}, f1 = {}, f2 = {}, f3 = {};

        PROD_LOAD(0);
        PROD_WRITE(phi0b, feat0b);       // tile 0 -> buf0 (pre-barrier, local)
        PROD_LOAD(64);                   // tile 1 regs

        for (int s = 0; s < 16; ++s) {
            __syncthreads();             // pairs with consumer barrier s
            if (s < 15) {
                unsigned short* wp = (s & 1) ? phi0b  : phi1b;
                unsigned short* wf = (s & 1) ? feat0b : feat1b;
                PROD_WRITE(wp, wf);      // tile s+1 from regs loaded last iter
                const int mnext = (s < 14 ? (s + 2) : 15) * 64;
                PROD_LOAD(mnext);        // consumed next iter -> full cover
            }
        }
    } else {
        // ================= CONSUMER waves 4-7 =================
        const int c  = wave - 4;         // rowgroup: n = 2c, 2c+1
        const int sw = l15 & 7;
#pragma unroll
        for (int ct = 0; ct < 7; ++ct) {
            acc0[ct] = (f32x4){0.f, 0.f, 0.f, 0.f};
            acc1[ct] = (f32x4){0.f, 0.f, 0.f, 0.f};
        }
        for (int s = 0; s < 16; ++s) {
            __syncthreads();             // pairs with producer barrier s
            GEMM1_7((s & 1) ? phi1b : phi0b, (s & 1) ? feat1b : feat0b);
        }
    }

    __syncthreads();   // all GEMM1 reads done -> phi bufs free for Tt

    // ---- acc (C: col=l15=i_local, row=q*4+r=k) -> Tt[n][k*104+i] (consumers)
    if (wave >= 4) {
        const int c = wave - 4;
#pragma unroll
        for (int ct = 0; ct < 7; ++ct) {
            int i = ct*16 + l15;
            if (i < DI) {
#pragma unroll
                for (int r = 0; r < 4; ++r) {
                    Tt[(2*c    )*TTST + (q*4+r)*DI + i] = f2b(acc0[ct][r]);
                    Tt[(2*c + 1)*TTST + (q*4+r)*DI + i] = f2b(acc1[ct][r]);
                }
            }
        }
    }
    __syncthreads();

    // ---- GEMM2: y[o,n] = sum_a Wp[a][o]*Tt[n][a]; 52 K-steps of 32 (all waves).
    // Wp pre-permuted: af/ag addresses LINEAR in s3 (no div/mod, no mad64).
    f32x4 y0 = (f32x4){0.f,0.f,0.f,0.f}, y1 = (f32x4){0.f,0.f,0.f,0.f};
    const unsigned short* wp0 = Wp + ((size_t)q*144 + (wave*16 + l15))*8;
    const unsigned short* wp1 = Wp + ((size_t)q*144 + (128 + l15))*8;
#pragma unroll 4
    for (int s3 = 0; s3 < 52; ++s3) {
        s16x8 bf = *(const s16x8*)(Tt + (l15 & 7)*TTST + s3*32 + q*8);
        s16x8 af = *(const s16x8*)(wp0 + (size_t)s3*4608);   // 4*144*8 elems/step
        y0 = __builtin_amdgcn_mfma_f32_16x16x32_bf16(af, bf, y0, 0, 0, 0);
        if (wave == 0) {
            s16x8 ag = *(const s16x8*)(wp1 + (size_t)s3*4608);
            y1 = __builtin_amdgcn_mfma_f32_16x16x32_bf16(ag, bf, y1, 0, 0, 0);
        }
    }
    if (l15 < 8) {
#pragma unroll
        for (int r = 0; r < 4; ++r)
            ylds[(wave*16 + q*4 + r)*YST + l15] = y0[r];
        if (wave == 0) {
#pragma unroll
            for (int r = 0; r < 4; ++r)
                ylds[(128 + q*4 + r)*YST + l15] = y1[r];
        }
    }
    __syncthreads();

    // ---- gating epilogue: out[b, o(<120), n0+nn] fp32 ----
    const float L2E = 1.4426950408889634f;
    for (int idx = t; idx < 120*8; idx += 512) {
        int o = idx >> 3, nn = idx & 7;
        float y = ylds[o*YST + nn];
        float v;
        if (o < 32) {
            v = fmaxf(y, 0.f);
        } else if (o < 80) {
            float g = ylds[(120 + (o-32)/3)*YST + nn];
            v = y * frcp_(1.f + fexp2(-g*L2E));
        } else {
            float g = ylds[(136 + (o-80)/5)*YST + nn];
            v = y * frcp_(1.f + fexp2(-g*L2E));
        }
        out_g[((size_t)(b*120 + o) << 10) + n0 + nn] = v;
    }
}

extern "C" void kernel_launch(void* const* d_in, const int* in_sizes, int n_in,
                              void* d_out, int out_size, void* d_ws, size_t ws_size,
                              hipStream_t stream) {
    const float* feat = (const float*)d_in[0];  // [4,104,1024] fp32
    const float* diff = (const float*)d_in[1];  // [4,1024,1024,3] fp32
    const float* mask = (const float*)d_in[2];  // [4,1024,1024] fp32
    const float* W    = (const float*)d_in[3];  // [16,144,104] fp32
    float* out = (float*)d_out;                 // [4,120,1024] fp32
    unsigned short* ws = (unsigned short*)d_ws; // Wp (479 KB) + featbf (852 KB)
    (void)in_sizes; (void)n_in; (void)out_size; (void)ws_size;
    cvt_kernel<<<dim3((W_ELEMS + F_ELEMS)/8/256), dim3(256), 0, stream>>>(feat, W, ws);
    pgb_kernel<<<dim3(512), dim3(512), 0, stream>>>(ws, diff, mask, out);
}

// Round 12
// 141.512 us; speedup vs baseline: 1.0039x; 1.0007x over previous
//
#include <hip/hip_runtime.h>

// PointGatedBlock: SE3 point conv + gated nonlinearity. fp32 in/out.
// R21 = R20 (wave specialization, 60.0us / best 58.1) + the MISSING combo
// piece: s_setprio(1) around consumer MFMA clusters (T5). Catalog evidence:
// setprio is null on lockstep schedules (m190, our R19) and +21-39% ONLY
// when waves have role diversity (m218b/m224) -- R20 built the role split
// (waves 0-3 producers: loads+phi trans+staging; waves 4-7 consumers:
// ds_read+MFMA) but never biased the CU scheduler toward the MFMA waves.
// Also: producer drops flog2(mask) -- multiply mask into the anchor after
// exp2 (algebraically identical, cleaner mask=0 edge): 16 -> 12 trans/thread.
// Everything else identical to R20: disjoint per-role loops with count-
// matched barriers (16 each), phi sequential recurrence per m-col, feat
// reg-staged by producers, GEMM2 Wp-linear, grid 512, 67KB LDS, 2 blk/CU,
// (512,4).

typedef __attribute__((ext_vector_type(4))) float f32x4;
typedef __attribute__((ext_vector_type(8))) short s16x8;

#define DI 104
#define DO 144
#define TTST 1688          // Tt row stride (elems)
#define YST 9

#define W_ELEMS 239616     // 16*144*104 (stored permuted: Wp[208][144][8])
#define F_ELEMS 425984     // 4*104*1024
#define WP_BLKS 29952      // 208*144 8-elem groups

// LDS byte offsets (phi/feat rows: 64 elems = 128 B, XOR-swizzled blocks)
#define OFF_PHI0 0
#define OFF_PHI1 16384                  // 128*64*2
#define OFF_FEAT0 32768
#define OFF_FEAT1 47104                 // + 112*64*2 = 14336
#define OFF_Y 61440
#define SMEM_TOTAL (61440 + 144*9*4)    // 66624 B -> 2 blocks/CU

__device__ __forceinline__ float fexp2(float x) {
#if __has_builtin(__builtin_amdgcn_exp2f)
    return __builtin_amdgcn_exp2f(x);
#else
    return exp2f(x);
#endif
}
__device__ __forceinline__ float fsqrt_(float x) {
#if __has_builtin(__builtin_amdgcn_sqrtf)
    return __builtin_amdgcn_sqrtf(x);
#else
    return sqrtf(x);
#endif
}
__device__ __forceinline__ float frcp_(float x) {
#if __has_builtin(__builtin_amdgcn_rcpf)
    return __builtin_amdgcn_rcpf(x);
#else
    return 1.0f / x;
#endif
}
__device__ __forceinline__ unsigned int pkbf(float lo, float hi) {
    unsigned int a = __builtin_bit_cast(unsigned int, lo) + 0x8000u;
    unsigned int b = __builtin_bit_cast(unsigned int, hi) + 0x8000u;
    return __builtin_amdgcn_perm(b, a, 0x07060302u);
}
__device__ __forceinline__ unsigned short f2b(float f) {
    return (unsigned short)((__builtin_bit_cast(unsigned int, f) + 0x8000u) >> 16);
}

// ---- pre-kernel: fp32 -> bf16. W permuted: Wp[a][o][8], a = k*13 + ib ----
__global__ __launch_bounds__(256, 8)
void cvt_kernel(const float* __restrict__ feat_g, const float* __restrict__ W_g,
                unsigned short* __restrict__ ws)
{
    int gid = blockIdx.x * 256 + threadIdx.x;           // 8 elems per thread
    const float* src;
    unsigned short* dst;
    if (gid < WP_BLKS) {
        int a = gid / 144;
        int o = gid - a * 144;
        int k = a / 13;
        int im = (a - k * 13) << 3;
        src = W_g + ((k * DO + o) * DI + im);
        dst = ws + gid * 8;
    } else {
        int g2 = gid - WP_BLKS;
        src = feat_g + g2 * 8;
        dst = ws + W_ELEMS + g2 * 8;
    }
    f32x4 a = *(const f32x4*)src;
    f32x4 b = *(const f32x4*)(src + 4);
    unsigned int o[4] = { pkbf(a[0],a[1]), pkbf(a[2],a[3]), pkbf(b[0],b[1]), pkbf(b[2],b[3]) };
    *(f32x4*)dst = *(f32x4*)o;
}

// ---- producer: load diff/mask (4 m-cols) + feat (4 chunks) for tile M0 ----
#define PROD_LOAD(M0)                                                  \
    do {                                                               \
        const float* dp_ = diff_g + (dmrow + (M0) + m0)*3;             \
        dA = *(const f32x4*)dp_;                                       \
        dB = *(const f32x4*)(dp_ + 4);                                 \
        dC = *(const f32x4*)(dp_ + 8);                                 \
        mkv = *(const f32x4*)(mask_g + dmrow + (M0) + m0);             \
        if (t < 208) {                                                 \
            const unsigned short* fp_ = featbf + fbase + ((size_t)frow << 10) + (M0) + (fc0 << 3); \
            f0 = *(const s16x8*)(fp_);                                 \
            f1 = *(const s16x8*)(fp_ + 8);                             \
            f2 = *(const s16x8*)(fp_ + 16);                            \
            f3 = *(const s16x8*)(fp_ + 24);                            \
        }                                                              \
    } while (0)

// ---- producer: phi (8 k-rows x 4 m-cols, sequential recurrence per col)
// + feat staging writes. Mask folded by POST-multiply (no log2):
// v0 = exp2(CEXP*(r-c)^2) * mask -- identical value, 4 fewer trans/thread.
#define PROD_WRITE(PBUF, FBUF)                                         \
    do {                                                               \
        float v0_, v1_, v2_, v3_, w0_, w1_, w2_, w3_;                  \
        { float r_ = fsqrt_(fmaf(dA[0],dA[0], fmaf(dA[1],dA[1], fmaf(dA[2],dA[2], 1e-12f)))); \
          float tt_ = r_ - K0OFF;                                      \
          v0_ = fexp2(CEXP*tt_*tt_) * mkv[0];                          \
          w0_ = fexp2(fmaf(A1, r_, S0B)); }                            \
        { float r_ = fsqrt_(fmaf(dA[3],dA[3], fmaf(dB[0],dB[0], fmaf(dB[1],dB[1], 1e-12f)))); \
          float tt_ = r_ - K0OFF;                                      \
          v1_ = fexp2(CEXP*tt_*tt_) * mkv[1];                          \
          w1_ = fexp2(fmaf(A1, r_, S0B)); }                            \
        { float r_ = fsqrt_(fmaf(dB[2],dB[2], fmaf(dB[3],dB[3], fmaf(dC[0],dC[0], 1e-12f)))); \
          float tt_ = r_ - K0OFF;                                      \
          v2_ = fexp2(CEXP*tt_*tt_) * mkv[2];                          \
          w2_ = fexp2(fmaf(A1, r_, S0B)); }                            \
        { float r_ = fsqrt_(fmaf(dC[1],dC[1], fmaf(dC[2],dC[2], fmaf(dC[3],dC[3], 1e-12f)))); \
          float tt_ = r_ - K0OFF;                                      \
          v3_ = fexp2(CEXP*tt_*tt_) * mkv[3];                          \
          w3_ = fexp2(fmaf(A1, r_, S0B)); }                            \
        unsigned short* pw_ = (PBUF) + pbase;                          \
        _Pragma("unroll")                                              \
        for (int j_ = 0; j_ < 8; ++j_) {                               \
            unsigned long long pk_ = (unsigned long long)pkbf(v0_, v1_) \
                                   | ((unsigned long long)pkbf(v2_, v3_) << 32); \
            *(unsigned long long*)(pw_ + j_*64 + ((pmblk ^ j_) << 3)) = pk_; \
            v0_ *= w0_; w0_ *= U2;                                     \
            v1_ *= w1_; w1_ *= U2;                                     \
            v2_ *= w2_; w2_ *= U2;                                     \
            v3_ *= w3_; w3_ *= U2;                                     \
        }                                                              \
        if (t < 208) {                                                 \
            unsigned short* fw_ = (FBUF) + frow*64;                    \
            *(s16x8*)(fw_ + (((fc0    ) ^ fsw) << 3)) = f0;            \
            *(s16x8*)(fw_ + (((fc0 + 1) ^ fsw) << 3)) = f1;            \
            *(s16x8*)(fw_ + (((fc0 + 2) ^ fsw) << 3)) = f2;            \
            *(s16x8*)(fw_ + (((fc0 + 3) ^ fsw) << 3)) = f3;            \
        }                                                              \
    } while (0)

// ---- consumer: one rowgroup (n = 2c, 2c+1) x all 7 coltiles, prio-boosted ----
#define GEMM1_7(PBUF, FBUF)                                            \
    do {                                                               \
        __builtin_amdgcn_s_setprio(1);                                 \
        _Pragma("unroll")                                              \
        for (int kk_ = 0; kk_ < 2; ++kk_) {                            \
            const int mo_ = ((kk_*4 + q) ^ sw) << 3;                   \
            s16x8 a0_ = *(const s16x8*)((PBUF) + (c*32      + l15)*64 + mo_); \
            s16x8 a1_ = *(const s16x8*)((PBUF) + (c*32 + 16 + l15)*64 + mo_); \
            _Pragma("unroll")                                          \
            for (int ct_ = 0; ct_ < 7; ++ct_) {                        \
                s16x8 bf_ = *(const s16x8*)((FBUF) + (ct_*16 + l15)*64 + mo_); \
                acc0[ct_] = __builtin_amdgcn_mfma_f32_16x16x32_bf16(a0_, bf_, acc0[ct_], 0, 0, 0); \
                acc1[ct_] = __builtin_amdgcn_mfma_f32_16x16x32_bf16(a1_, bf_, acc1[ct_], 0, 0, 0); \
            }                                                          \
        }                                                              \
        __builtin_amdgcn_s_setprio(0);                                 \
    } while (0)

__global__ __launch_bounds__(512, 4)
void pgb_kernel(const unsigned short* __restrict__ ws,   // Wp | featbf
                const float* __restrict__ diff_g,
                const float* __restrict__ mask_g,
                float* __restrict__ out_g)
{
    const unsigned short* Wp     = ws;                   // [208][144][8] bf16
    const unsigned short* featbf = ws + W_ELEMS;

    __shared__ __align__(16) unsigned char smem[SMEM_TOTAL];
    unsigned short* Tt   = (unsigned short*)smem;        // aliases phi bufs (post-loop)
    float*          ylds = (float*)(smem + OFF_Y);
    unsigned short* phi0b  = (unsigned short*)(smem + OFF_PHI0);
    unsigned short* phi1b  = (unsigned short*)(smem + OFF_PHI1);
    unsigned short* feat0b = (unsigned short*)(smem + OFF_FEAT0);
    unsigned short* feat1b = (unsigned short*)(smem + OFF_FEAT1);

    const int t    = threadIdx.x;
    const int b    = blockIdx.x >> 7;
    const int n0   = (blockIdx.x & 127) << 3;
    const int wave = t >> 6;
    const int lane = t & 63;
    const int l15  = lane & 15;
    const int q    = lane >> 4;

    // zero feat pad rows 104..111 in both buffers (threads 0..255 = producers)
    if (t < 256) {
        ((unsigned int*)(smem + OFF_FEAT0 + DI*128))[t] = 0u;
        ((unsigned int*)(smem + OFF_FEAT1 + DI*128))[t] = 0u;
    }

    f32x4 acc0[7], acc1[7];              // consumer accumulators

    if (wave < 4) {
        // ================= PRODUCER waves 0-3 =================
        const int pn    = t >> 5;        // n-row 0..7
        const int kh    = (t >> 4) & 1;  // k-half: k0 = 8*kh
        const int mg    = t & 15;        // m-group: cols m0..m0+3
        const int m0    = mg << 2;
        const int pmblk = mg >> 1;       // 8-elem block index of m0
        const int pbase = (pn*16 + kh*8)*64 + (m0 & 7);
        const int frow  = t >> 1;        // feat row 0..103 (t<208)
        const int fc0   = (t & 1) << 2;  // first 16B chunk (of 8) in the row
        const int fsw   = frow & 7;
        const float CEXP = -23.083120654223414f;   // -GAMMA * log2(e)
        const float A1   = 6.155498841126244f;     // -2*CEXP*DL
        const float V2   = -0.8207331788168325f;   // 2*CEXP*DL^2
        const float U2   = fexp2(V2);
        const float K0OFF = kh ? 1.0666666666666667f : 0.f;
        const float S0B   = kh ? -6.976232019943076f : -0.41036658940841624f;
        const size_t dmrow = (size_t)((b << 10) + n0 + pn) << 10;
        const size_t fbase = (size_t)b * DI << 10;

        f32x4 dA, dB, dC, mkv;
        s16x8 f0 = {}, f1 = {}, f2 = {}, f3 = {};

        PROD_LOAD(0);
        PROD_WRITE(phi0b, feat0b);       // tile 0 -> buf0 (pre-barrier, local)
        PROD_LOAD(64);                   // tile 1 regs

        for (int s = 0; s < 16; ++s) {
            __syncthreads();             // pairs with consumer barrier s
            if (s < 15) {
                unsigned short* wp = (s & 1) ? phi0b  : phi1b;
                unsigned short* wf = (s & 1) ? feat0b : feat1b;
                PROD_WRITE(wp, wf);      // tile s+1 from regs loaded last iter
                const int mnext = (s < 14 ? (s + 2) : 15) * 64;
                PROD_LOAD(mnext);        // consumed next iter -> full cover
            }
        }
    } else {
        // ================= CONSUMER waves 4-7 =================
        const int c  = wave - 4;         // rowgroup: n = 2c, 2c+1
        const int sw = l15 & 7;
#pragma unroll
        for (int ct = 0; ct < 7; ++ct) {
            acc0[ct] = (f32x4){0.f, 0.f, 0.f, 0.f};
            acc1[ct] = (f32x4){0.f, 0.f, 0.f, 0.f};
        }
        for (int s = 0; s < 16; ++s) {
            __syncthreads();             // pairs with producer barrier s
            GEMM1_7((s & 1) ? phi1b : phi0b, (s & 1) ? feat1b : feat0b);
        }
    }

    __syncthreads();   // all GEMM1 reads done -> phi bufs free for Tt

    // ---- acc (C: col=l15=i_local, row=q*4+r=k) -> Tt[n][k*104+i] (consumers)
    if (wave >= 4) {
        const int c = wave - 4;
#pragma unroll
        for (int ct = 0; ct < 7; ++ct) {
            int i = ct*16 + l15;
            if (i < DI) {
#pragma unroll
                for (int r = 0; r < 4; ++r) {
                    Tt[(2*c    )*TTST + (q*4+r)*DI + i] = f2b(acc0[ct][r]);
                    Tt[(2*c + 1)*TTST + (q*4+r)*DI + i] = f2b(acc1[ct][r]);
                }
            }
        }
    }
    __syncthreads();

    // ---- GEMM2: y[o,n] = sum_a Wp[a][o]*Tt[n][a]; 52 K-steps of 32 (all waves).
    f32x4 y0 = (f32x4){0.f,0.f,0.f,0.f}, y1 = (f32x4){0.f,0.f,0.f,0.f};
    const unsigned short* wp0 = Wp + ((size_t)q*144 + (wave*16 + l15))*8;
    const unsigned short* wp1 = Wp + ((size_t)q*144 + (128 + l15))*8;
    __builtin_amdgcn_s_setprio(1);
#pragma unroll 4
    for (int s3 = 0; s3 < 52; ++s3) {
        s16x8 bf = *(const s16x8*)(Tt + (l15 & 7)*TTST + s3*32 + q*8);
        s16x8 af = *(const s16x8*)(wp0 + (size_t)s3*4608);   // 4*144*8 elems/step
        y0 = __builtin_amdgcn_mfma_f32_16x16x32_bf16(af, bf, y0, 0, 0, 0);
        if (wave == 0) {
            s16x8 ag = *(const s16x8*)(wp1 + (size_t)s3*4608);
            y1 = __builtin_amdgcn_mfma_f32_16x16x32_bf16(ag, bf, y1, 0, 0, 0);
        }
    }
    __builtin_amdgcn_s_setprio(0);
    if (l15 < 8) {
#pragma unroll
        for (int r = 0; r < 4; ++r)
            ylds[(wave*16 + q*4 + r)*YST + l15] = y0[r];
        if (wave == 0) {
#pragma unroll
            for (int r = 0; r < 4; ++r)
                ylds[(128 + q*4 + r)*YST + l15] = y1[r];
        }
    }
    __syncthreads();

    // ---- gating epilogue: out[b, o(<120), n0+nn] fp32 ----
    const float L2E = 1.4426950408889634f;
    for (int idx = t; idx < 120*8; idx += 512) {
        int o = idx >> 3, nn = idx & 7;
        float y = ylds[o*YST + nn];
        float v;
        if (o < 32) {
            v = fmaxf(y, 0.f);
        } else if (o < 80) {
            float g = ylds[(120 + (o-32)/3)*YST + nn];
            v = y * frcp_(1.f + fexp2(-g*L2E));
        } else {
            float g = ylds[(136 + (o-80)/5)*YST + nn];
            v = y * frcp_(1.f + fexp2(-g*L2E));
        }
        out_g[((size_t)(b*120 + o) << 10) + n0 + nn] = v;
    }
}

extern "C" void kernel_launch(void* const* d_in, const int* in_sizes, int n_in,
                              void* d_out, int out_size, void* d_ws, size_t ws_size,
                              hipStream_t stream) {
    const float* feat = (const float*)d_in[0];  // [4,104,1024] fp32
    const float* diff = (const float*)d_in[1];  // [4,1024,1024,3] fp32
    const float* mask = (const float*)d_in[2];  // [4,1024,1024] fp32
    const float* W    = (const float*)d_in[3];  // [16,144,104] fp32
    float* out = (float*)d_out;                 // [4,120,1024] fp32
    unsigned short* ws = (unsigned short*)d_ws; // Wp (479 KB) + featbf (852 KB)
    (void)in_sizes; (void)n_in; (void)out_size; (void)ws_size;
    cvt_kernel<<<dim3((W_ELEMS + F_ELEMS)/8/256), dim3(256), 0, stream>>>(feat, W, ws);
    pgb_kernel<<<dim3(512), dim3(512), 0, stream>>>(ws, diff, mask, out);
}